// Round 2
// baseline (20229.604 us; speedup 1.0000x reference)
//
#include <hip/hip_runtime.h>
#include <math.h>
#include <stdint.h>

#define B_     1024
#define DD     256
#define UN     512
#define TSTEPS 100
#define LDO    (TSTEPS * DD)   // 25600

typedef _Float16 f16x8 __attribute__((ext_vector_type(8)));
typedef float    f32x4 __attribute__((ext_vector_type(4)));

// ---------------------------------------------------------------------------
// Weight pack: fp32 [K][NC] -> fragment-linear fp16 hi/lo.
// Frag (kt, ut, g, hl): lane l, elem i  <-  src[kt*32 + (l>>4)*8 + i][ut*16 + (l&15) + g*GS]
// hl=0: hi = (f16)x ; hl=1: lo = (f16)((x - hi)*2048)
// Frag linear index = kt*(NUT*NG*2) + (ut*NG + g)*2 + hl, each frag 512 halves (1KB).
// ---------------------------------------------------------------------------
__global__ __launch_bounds__(128) void pack_k(
    const float* __restrict__ src, _Float16* __restrict__ dst,
    int NC, int GS, int NG, int NUT)
{
    const int kt = blockIdx.x;
    const int ut = blockIdx.y;
    const int FPK = NUT * NG * 2;
    const int tot = NG * 2 * 64;
    for (int e = threadIdx.x; e < tot; e += 128) {
        const int lane = e & 63;
        const int hl   = (e >> 6) & 1;
        const int g    = e >> 7;
        const int lr = lane & 15, lg2 = lane >> 4;
        f16x8 v;
#pragma unroll
        for (int i = 0; i < 8; ++i) {
            const int k = kt * 32 + lg2 * 8 + i;
            const float x = src[(size_t)k * NC + ut * 16 + lr + g * GS];
            const _Float16 h = (_Float16)x;
            v[i] = hl ? (_Float16)((x - (float)h) * 2048.0f) : h;
        }
        const size_t base = ((size_t)kt * FPK + (ut * NG + g) * 2 + hl) * 512 + lane * 8;
        *(f16x8*)(dst + base) = v;
    }
}

// ---------------------------------------------------------------------------
// Fused LSTM step: z = A@W + Hp@U + b (split-fp16, 3-MFMA correction), then cell.
// Grid (16, 32), block 128 (2 waves). Wave tile 32m x (16 units x 4 gates).
// ---------------------------------------------------------------------------
template<bool XF32>
__global__ __launch_bounds__(128) void lstm_mfma_k(
    const void* __restrict__ Asrc_h, const void* __restrict__ Asrc_l, int ldaA, int KTA,
    const _Float16* __restrict__ packW,
    const _Float16* __restrict__ Hph, const _Float16* __restrict__ Hpl,
    const _Float16* __restrict__ packU,
    const float* __restrict__ bias,
    float* __restrict__ Cst,
    _Float16* __restrict__ Hh, _Float16* __restrict__ Hl)
{
    __shared__ __align__(16) _Float16 lds[2][8 * 512];
    const int tid  = threadIdx.x;
    const int wid  = tid >> 6, lane = tid & 63;
    const int lr   = lane & 15, lg2 = lane >> 4;
    const int m0   = blockIdx.x * 64 + wid * 32;
    const int utg  = blockIdx.y;            // unit tile 0..31
    const int KT   = KTA + 16;

    f32x4 acch[2][4], accl[2][4];
#pragma unroll
    for (int mf = 0; mf < 2; ++mf)
#pragma unroll
        for (int g = 0; g < 4; ++g) { acch[mf][g] = (f32x4)0.0f; accl[mf][g] = (f32x4)0.0f; }

    auto loadA = [&](f16x8 (&a)[2][2], int kt) {
        if (kt < KTA) {
            const size_t ko = (size_t)kt * 32 + lg2 * 8;
            if (XF32) {
                const float* X = (const float*)Asrc_h;
#pragma unroll
                for (int mf = 0; mf < 2; ++mf) {
                    const float* p = X + (size_t)(m0 + mf * 16 + lr) * ldaA + ko;
#pragma unroll
                    for (int i = 0; i < 8; ++i) {
                        const float x = p[i];
                        const _Float16 h = (_Float16)x;
                        a[mf][0][i] = h;
                        a[mf][1][i] = (_Float16)((x - (float)h) * 2048.0f);
                    }
                }
            } else {
                const _Float16* Ah = (const _Float16*)Asrc_h;
                const _Float16* Al = (const _Float16*)Asrc_l;
#pragma unroll
                for (int mf = 0; mf < 2; ++mf) {
                    const size_t off = (size_t)(m0 + mf * 16 + lr) * ldaA + ko;
                    a[mf][0] = *(const f16x8*)(Ah + off);
                    a[mf][1] = *(const f16x8*)(Al + off);
                }
            }
        } else {
            const size_t ko = (size_t)(kt - KTA) * 32 + lg2 * 8;
#pragma unroll
            for (int mf = 0; mf < 2; ++mf) {
                const size_t off = (size_t)(m0 + mf * 16 + lr) * UN + ko;
                a[mf][0] = *(const f16x8*)(Hph + off);
                a[mf][1] = *(const f16x8*)(Hpl + off);
            }
        }
    };

    auto loadB = [&](f16x8 (&bs)[4], int kt) {
        const _Float16* pk = (kt < KTA) ? packW : packU;
        const size_t base = (size_t)((kt < KTA) ? kt : kt - KTA) * 256;  // FPK = 256 frags/kt
#pragma unroll
        for (int q = 0; q < 4; ++q) {
            const int f = wid * 4 + q;  // 0..7 = g*2+hl
            bs[q] = *(const f16x8*)(pk + (base + utg * 8 + f) * 512 + lane * 8);
        }
    };

    auto stage = [&](const f16x8 (&bs)[4], int buf) {
#pragma unroll
        for (int q = 0; q < 4; ++q)
            *(f16x8*)&lds[buf][(wid * 4 + q) * 512 + lane * 8] = bs[q];
    };

    auto comp = [&](const f16x8 (&a)[2][2], int buf) {
        f16x8 b[4][2];
#pragma unroll
        for (int g = 0; g < 4; ++g) {
            b[g][0] = *(const f16x8*)&lds[buf][(g * 2 + 0) * 512 + lane * 8];
            b[g][1] = *(const f16x8*)&lds[buf][(g * 2 + 1) * 512 + lane * 8];
        }
#pragma unroll
        for (int mf = 0; mf < 2; ++mf)
#pragma unroll
            for (int g = 0; g < 4; ++g) {
                acch[mf][g] = __builtin_amdgcn_mfma_f32_16x16x32_f16(a[mf][0], b[g][0], acch[mf][g], 0, 0, 0);
                accl[mf][g] = __builtin_amdgcn_mfma_f32_16x16x32_f16(a[mf][0], b[g][1], accl[mf][g], 0, 0, 0);
                accl[mf][g] = __builtin_amdgcn_mfma_f32_16x16x32_f16(a[mf][1], b[g][0], accl[mf][g], 0, 0, 0);
            }
    };

    f16x8 aA[2][2], aB[2][2], bsA[4], bsB[4];
    loadB(bsA, 0); loadA(aA, 0);
    stage(bsA, 0);
    __syncthreads();
    for (int kt = 0; kt < KT; kt += 2) {
        if (kt + 1 < KT) { loadB(bsB, kt + 1); loadA(aB, kt + 1); }
        comp(aA, 0);
        if (kt + 1 < KT) stage(bsB, 1);
        __syncthreads();
        if (kt + 1 >= KT) break;
        if (kt + 2 < KT) { loadB(bsA, kt + 2); loadA(aA, kt + 2); }
        comp(aB, 1);
        if (kt + 2 < KT) stage(bsA, 0);
        __syncthreads();
    }

    // epilogue: lane-local LSTM cell (Keras order i,f,g,o across the 4 n-frags)
    const int u = utg * 16 + lr;
    float bz[4];
#pragma unroll
    for (int g = 0; g < 4; ++g) bz[g] = bias[u + (g << 9)];
#pragma unroll
    for (int mf = 0; mf < 2; ++mf)
#pragma unroll
        for (int r = 0; r < 4; ++r) {
            const int m = m0 + mf * 16 + lg2 * 4 + r;
            float z[4];
#pragma unroll
            for (int g = 0; g < 4; ++g)
                z[g] = acch[mf][g][r] + accl[mf][g][r] * (1.0f / 2048.0f) + bz[g];
            const float i_ = 1.f / (1.f + expf(-z[0]));
            const float f_ = 1.f / (1.f + expf(-z[1]));
            const float g_ = tanhf(z[2]);
            const float o_ = 1.f / (1.f + expf(-z[3]));
            const size_t idx = (size_t)m * UN + u;
            const float c_ = f_ * Cst[idx] + i_ * g_;
            Cst[idx] = c_;
            const float h = o_ * tanhf(c_);
            const _Float16 hh = (_Float16)h;
            Hh[idx] = hh;
            Hl[idx] = (_Float16)((h - (float)hh) * 2048.0f);
        }
}

// ---------------------------------------------------------------------------
// Decoder: out = H @ Wd + bd (split-fp16). Also emits hi/lo fp16 pred for AR.
// Grid (16, 4), block 128. Wave tile 32m x 64n.
// ---------------------------------------------------------------------------
__global__ __launch_bounds__(128) void dec_mfma_k(
    const _Float16* __restrict__ Ah, const _Float16* __restrict__ Al,
    const _Float16* __restrict__ packD,
    const float* __restrict__ bd,
    float* __restrict__ out,      // pre-offset by a*256
    _Float16* __restrict__ Ph, _Float16* __restrict__ Pl)
{
    __shared__ __align__(16) _Float16 lds[2][8 * 512];
    const int tid = threadIdx.x;
    const int wid = tid >> 6, lane = tid & 63;
    const int lr  = lane & 15, lg2 = lane >> 4;
    const int m0  = blockIdx.x * 64 + wid * 32;
    const int nt0 = blockIdx.y;           // 0..3, block n-span 64
    const int KT  = 16;                   // K = 512

    f32x4 acch[2][4], accl[2][4];
#pragma unroll
    for (int mf = 0; mf < 2; ++mf)
#pragma unroll
        for (int g = 0; g < 4; ++g) { acch[mf][g] = (f32x4)0.0f; accl[mf][g] = (f32x4)0.0f; }

    auto loadA = [&](f16x8 (&a)[2][2], int kt) {
        const size_t ko = (size_t)kt * 32 + lg2 * 8;
#pragma unroll
        for (int mf = 0; mf < 2; ++mf) {
            const size_t off = (size_t)(m0 + mf * 16 + lr) * UN + ko;
            a[mf][0] = *(const f16x8*)(Ah + off);
            a[mf][1] = *(const f16x8*)(Al + off);
        }
    };
    auto loadB = [&](f16x8 (&bs)[4], int kt) {
#pragma unroll
        for (int q = 0; q < 4; ++q) {
            const int f = wid * 4 + q;  // 0..7 = nf*2+hl
            bs[q] = *(const f16x8*)(packD + ((size_t)kt * 32 + nt0 * 8 + f) * 512 + lane * 8);
        }
    };
    auto stage = [&](const f16x8 (&bs)[4], int buf) {
#pragma unroll
        for (int q = 0; q < 4; ++q)
            *(f16x8*)&lds[buf][(wid * 4 + q) * 512 + lane * 8] = bs[q];
    };
    auto comp = [&](const f16x8 (&a)[2][2], int buf) {
        f16x8 b[4][2];
#pragma unroll
        for (int nf = 0; nf < 4; ++nf) {
            b[nf][0] = *(const f16x8*)&lds[buf][(nf * 2 + 0) * 512 + lane * 8];
            b[nf][1] = *(const f16x8*)&lds[buf][(nf * 2 + 1) * 512 + lane * 8];
        }
#pragma unroll
        for (int mf = 0; mf < 2; ++mf)
#pragma unroll
            for (int nf = 0; nf < 4; ++nf) {
                acch[mf][nf] = __builtin_amdgcn_mfma_f32_16x16x32_f16(a[mf][0], b[nf][0], acch[mf][nf], 0, 0, 0);
                accl[mf][nf] = __builtin_amdgcn_mfma_f32_16x16x32_f16(a[mf][0], b[nf][1], accl[mf][nf], 0, 0, 0);
                accl[mf][nf] = __builtin_amdgcn_mfma_f32_16x16x32_f16(a[mf][1], b[nf][0], accl[mf][nf], 0, 0, 0);
            }
    };

    f16x8 aA[2][2], aB[2][2], bsA[4], bsB[4];
    loadB(bsA, 0); loadA(aA, 0);
    stage(bsA, 0);
    __syncthreads();
    for (int kt = 0; kt < KT; kt += 2) {
        if (kt + 1 < KT) { loadB(bsB, kt + 1); loadA(aB, kt + 1); }
        comp(aA, 0);
        if (kt + 1 < KT) stage(bsB, 1);
        __syncthreads();
        if (kt + 1 >= KT) break;
        if (kt + 2 < KT) { loadB(bsA, kt + 2); loadA(aA, kt + 2); }
        comp(aB, 1);
        if (kt + 2 < KT) stage(bsA, 0);
        __syncthreads();
    }

    const int n0 = nt0 * 64;
#pragma unroll
    for (int mf = 0; mf < 2; ++mf)
#pragma unroll
        for (int r = 0; r < 4; ++r) {
            const int m = m0 + mf * 16 + lg2 * 4 + r;
#pragma unroll
            for (int nf = 0; nf < 4; ++nf) {
                const int n = n0 + nf * 16 + lr;
                const float z = acch[mf][nf][r] + accl[mf][nf][r] * (1.0f / 2048.0f) + bd[n];
                out[(size_t)m * LDO + n] = z;
                const _Float16 zh = (_Float16)z;
                Ph[(size_t)m * DD + n] = zh;
                Pl[(size_t)m * DD + n] = (_Float16)((z - (float)zh) * 2048.0f);
            }
        }
}

// ---------------------------------------------------------------------------
extern "C" void kernel_launch(void* const* d_in, const int* in_sizes, int n_in,
                              void* d_out, int out_size, void* d_ws, size_t ws_size,
                              hipStream_t stream)
{
    const float* x    = (const float*)d_in[0];
    const float* W[3] = {(const float*)d_in[1], (const float*)d_in[4], (const float*)d_in[7]};
    const float* U[3] = {(const float*)d_in[2], (const float*)d_in[5], (const float*)d_in[8]};
    const float* bv[3]= {(const float*)d_in[3], (const float*)d_in[6], (const float*)d_in[9]};
    const float* Wd   = (const float*)d_in[10];
    const float* bd   = (const float*)d_in[11];
    float* out = (float*)d_out;

    uint8_t* p = (uint8_t*)d_ws;
    auto alloc = [&](size_t bytes) { uint8_t* r = p; p += (bytes + 255) & ~(size_t)255; return r; };

    _Float16* pW[3]; _Float16* pU[3];
    pW[0] = (_Float16*)alloc((size_t)256 * 2048 * 2 * 2);
    pU[0] = (_Float16*)alloc((size_t)512 * 2048 * 2 * 2);
    pW[1] = (_Float16*)alloc((size_t)512 * 2048 * 2 * 2);
    pU[1] = (_Float16*)alloc((size_t)512 * 2048 * 2 * 2);
    pW[2] = (_Float16*)alloc((size_t)512 * 2048 * 2 * 2);
    pU[2] = (_Float16*)alloc((size_t)512 * 2048 * 2 * 2);
    _Float16* pD = (_Float16*)alloc((size_t)512 * 256 * 2 * 2);

    const size_t HSZ = (size_t)B_ * UN;             // 524288
    uint8_t* zbase = p;
    _Float16 *hh[3][2], *hl[3][2]; float* Cb[3];
    for (int j = 0; j < 3; ++j)
        for (int b2 = 0; b2 < 2; ++b2) {
            hh[j][b2] = (_Float16*)alloc(HSZ * 2);
            hl[j][b2] = (_Float16*)alloc(HSZ * 2);
        }
    for (int j = 0; j < 3; ++j) Cb[j] = (float*)alloc(HSZ * 4);
    const size_t zbytes = (size_t)(p - zbase);
    _Float16* t0h = (_Float16*)alloc(HSZ * 2);
    _Float16* t0l = (_Float16*)alloc(HSZ * 2);
    _Float16* ph  = (_Float16*)alloc((size_t)B_ * DD * 2);
    _Float16* pl  = (_Float16*)alloc((size_t)B_ * DD * 2);

    hipMemsetAsync(zbase, 0, zbytes, stream);

    // ---- weight packing (runs every call; ws is re-poisoned each launch) ----
    pack_k<<<dim3(8, 32),  128, 0, stream>>>(W[0], pW[0], 2048, 512, 4, 32);
    pack_k<<<dim3(16, 32), 128, 0, stream>>>(U[0], pU[0], 2048, 512, 4, 32);
    pack_k<<<dim3(16, 32), 128, 0, stream>>>(W[1], pW[1], 2048, 512, 4, 32);
    pack_k<<<dim3(16, 32), 128, 0, stream>>>(U[1], pU[1], 2048, 512, 4, 32);
    pack_k<<<dim3(16, 32), 128, 0, stream>>>(W[2], pW[2], 2048, 512, 4, 32);
    pack_k<<<dim3(16, 32), 128, 0, stream>>>(U[2], pU[2], 2048, 512, 4, 32);
    pack_k<<<dim3(16, 16), 128, 0, stream>>>(Wd,   pD,    256,  0,   1, 16);

    const dim3 bs(128);
    const dim3 gl(16, 32);   // LSTM: 1024/64 x 2048/64
    const dim3 gd(16, 4);    // dec : 1024/64 x 256/64

    // ---- warmup: wavefront over layers (layer j at step s handles t = s-j) ----
    for (int s = 0; s < TSTEPS + 2; ++s) {
        const int ri = s & 1, wi = ri ^ 1;
        if (s < TSTEPS)
            lstm_mfma_k<true><<<gl, bs, 0, stream>>>(
                x + (size_t)s * DD, nullptr, LDO, 8, pW[0],
                hh[0][ri], hl[0][ri], pU[0], bv[0], Cb[0], hh[0][wi], hl[0][wi]);
        for (int j = 1; j < 3; ++j) {
            const int t = s - j;
            if (t < 0 || t >= TSTEPS) continue;
            lstm_mfma_k<false><<<gl, bs, 0, stream>>>(
                hh[j - 1][ri], hl[j - 1][ri], UN, 16, pW[j],
                hh[j][ri], hl[j][ri], pU[j], bv[j], Cb[j], hh[j][wi], hl[j][wi]);
        }
        if (s == 2) {  // layer2's t=0 output (in buf 1) before it's overwritten (s=4)
            hipMemcpyAsync(t0h, hh[2][1], HSZ * 2, hipMemcpyDeviceToDevice, stream);
            hipMemcpyAsync(t0l, hl[2][1], HSZ * 2, hipMemcpyDeviceToDevice, stream);
        }
    }

    // pred0
    dec_mfma_k<<<gd, bs, 0, stream>>>(t0h, t0l, pD, bd, out, ph, pl);

    // ---- autoregressive rollout ----
    int cur[3] = {0, 1, 0};   // final warmup h locations
    for (int a = 1; a < TSTEPS; ++a) {
        lstm_mfma_k<false><<<gl, bs, 0, stream>>>(
            ph, pl, DD, 8, pW[0],
            hh[0][cur[0]], hl[0][cur[0]], pU[0], bv[0], Cb[0],
            hh[0][cur[0] ^ 1], hl[0][cur[0] ^ 1]);
        cur[0] ^= 1;
        for (int j = 1; j < 3; ++j) {
            lstm_mfma_k<false><<<gl, bs, 0, stream>>>(
                hh[j - 1][cur[j - 1]], hl[j - 1][cur[j - 1]], UN, 16, pW[j],
                hh[j][cur[j]], hl[j][cur[j]], pU[j], bv[j], Cb[j],
                hh[j][cur[j] ^ 1], hl[j][cur[j] ^ 1]);
            cur[j] ^= 1;
        }
        dec_mfma_k<<<gd, bs, 0, stream>>>(hh[2][cur[2]], hl[2][cur[2]], pD, bd,
                                          out + (size_t)a * DD, ph, pl);
    }
}